// Round 5
// baseline (74.555 us; speedup 1.0000x reference)
//
#include <hip/hip_runtime.h>
#include <math.h>

// EnforceDecrease: one workgroup per spike n.
//   ptps = wf.max(T) - wf.min(T)                         (per channel)
//   parent_min = min over P parents of padded ptps       (pad idx c -> +inf)
//   resc = min(parent_min / ptps, 1)
//   out0 = wf * resc[:, None, :]   out1 = ptps * resc
//
// N=8192, T=121, c=40, C=384, P=12. Waveform tile = 4840 f32 = 19.36 KB LDS
// -> 8 blocks/CU resident (32 waves/CU, full occupancy). Memory-bound:
// ~318 MB total HBM traffic, single read of waveforms via LDS staging.

#define N_T 121
#define N_C 40
#define N_P 12
#define TPB 256
#define WF_ELEMS (N_T * N_C)   // 4840, divisible by 4

__global__ __launch_bounds__(TPB) void enforce_decrease_kernel(
    const float* __restrict__ waveforms,
    const int*   __restrict__ max_channels,
    const int*   __restrict__ parents_index,
    float*       __restrict__ out,
    int n_total)
{
    __shared__ float wf[WF_ELEMS];
    __shared__ float pmx[6 * N_C];
    __shared__ float pmn[6 * N_C];
    __shared__ float ptp[N_C];
    __shared__ float resc[N_C];

    const int n   = blockIdx.x;
    const int tid = threadIdx.x;

    // ---- Stage waveform n into LDS with float4 loads (coalesced, 16B/lane).
    const float4* src4 = (const float4*)(waveforms + (size_t)n * WF_ELEMS);
    float4*       wf4  = (float4*)wf;
    #pragma unroll
    for (int i = tid; i < WF_ELEMS / 4; i += TPB)
        wf4[i] = src4[i];
    __syncthreads();

    // ---- Per-channel max/min, 6-way split over T.
    // thread = ch + 40*g (g in 0..5). For iteration k the wave reads LDS
    // address 240*k + tid -> contiguous, conflict-free.
    if (tid < 6 * N_C) {
        const int ch = tid % N_C;
        const int g  = tid / N_C;
        float mx = -INFINITY, mn = INFINITY;
        for (int t = g; t < N_T; t += 6) {
            const float v = wf[t * N_C + ch];
            mx = fmaxf(mx, v);
            mn = fminf(mn, v);
        }
        pmx[tid] = mx;
        pmn[tid] = mn;
    }
    __syncthreads();

    // ---- Reduce the 6 partials -> ptp per channel.
    if (tid < N_C) {
        float mx = pmx[tid], mn = pmn[tid];
        #pragma unroll
        for (int g = 1; g < 6; ++g) {
            mx = fmaxf(mx, pmx[g * N_C + tid]);
            mn = fminf(mn, pmn[g * N_C + tid]);
        }
        ptp[tid] = mx - mn;
    }
    __syncthreads();

    // ---- Parent-min gather + rescaling + decreasing_ptps output.
    if (tid < N_C) {
        const int  mc   = max_channels[n];
        const int* prow = parents_index + mc * (N_C * N_P) + tid * N_P;
        float minp = INFINITY;
        #pragma unroll
        for (int p = 0; p < N_P; ++p) {
            const int idx = prow[p];
            minp = fminf(minp, (idx >= N_C) ? INFINITY : ptp[idx]);
        }
        const float r = fminf(minp / ptp[tid], 1.0f);
        resc[tid] = r;
        // decreasing_ptps, second output, offset N*T*c
        out[(size_t)n_total * WF_ELEMS + (size_t)n * N_C + tid] = ptp[tid] * r;
    }
    __syncthreads();

    // ---- Rescaled waveform from LDS, float4 stores.
    // 40 % 4 == 0 -> channels of one quad are ch0..ch0+3, never wrapping.
    float4* dst4 = (float4*)(out + (size_t)n * WF_ELEMS);
    #pragma unroll
    for (int i = tid; i < WF_ELEMS / 4; i += TPB) {
        float4 v = wf4[i];
        const int ch0 = (i * 4) % N_C;
        v.x *= resc[ch0];
        v.y *= resc[ch0 + 1];
        v.z *= resc[ch0 + 2];
        v.w *= resc[ch0 + 3];
        dst4[i] = v;
    }
}

extern "C" void kernel_launch(void* const* d_in, const int* in_sizes, int n_in,
                              void* d_out, int out_size, void* d_ws, size_t ws_size,
                              hipStream_t stream) {
    const float* waveforms     = (const float*)d_in[0];
    const int*   max_channels  = (const int*)d_in[1];
    const int*   parents_index = (const int*)d_in[2];
    float*       out           = (float*)d_out;

    const int n = in_sizes[1];  // N = 8192 (element count of max_channels)

    enforce_decrease_kernel<<<dim3(n), dim3(TPB), 0, stream>>>(
        waveforms, max_channels, parents_index, out, n);
}

// Round 6
// 65.446 us; speedup vs baseline: 1.1392x; 1.1392x over previous
//
#include <hip/hip_runtime.h>
#include <math.h>

// EnforceDecrease: one workgroup per spike n.
//   ptps = wf.max(T) - wf.min(T)                         (per channel)
//   parent_min = min over P parents of padded ptps       (pad idx c -> +inf)
//   resc = min(parent_min / ptps, 1)
//   out0 = wf * resc[:, None, :]   out1 = ptps * resc
//
// R5 change: stage waveform with __builtin_amdgcn_global_load_lds (16B DMA,
// no VGPR round-trip). R5 diagnosis: read path was outstanding-request
// limited (~5 float4/thread in flight); DMA staging lets each wave issue all
// its staging loads before stalling at the barrier.

#define N_T 121
#define N_C 40
#define N_P 12
#define TPB 256
#define WF_ELEMS (N_T * N_C)      // 4840 floats
#define WF_QUADS (WF_ELEMS / 4)   // 1210 float4 quads
#define FULL_K   (WF_QUADS / TPB) // 4 full rounds = 1024 quads
#define TAIL_Q   (WF_QUADS - FULL_K * TPB) // 186 tail quads

#define GLOAD_LDS16(g, l)                                              \
    __builtin_amdgcn_global_load_lds(                                  \
        (const __attribute__((address_space(1))) void*)(g),            \
        (__attribute__((address_space(3))) void*)(l), 16, 0, 0)

__global__ __launch_bounds__(TPB) void enforce_decrease_kernel(
    const float* __restrict__ waveforms,
    const int*   __restrict__ max_channels,
    const int*   __restrict__ parents_index,
    float*       __restrict__ out,
    int n_total)
{
    __shared__ float wf[WF_ELEMS];
    __shared__ float pmx[6 * N_C];
    __shared__ float pmn[6 * N_C];
    __shared__ float ptp[N_C];
    __shared__ float resc[N_C];

    const int n   = blockIdx.x;
    const int tid = threadIdx.x;

    // ---- Stage waveform n into LDS via direct global->LDS DMA.
    // LDS layout is linear in lane order (quad i -> LDS byte 16*i), which is
    // exactly the wave-uniform-base + lane*16 pattern the DMA requires.
    const float* src = waveforms + (size_t)n * WF_ELEMS;
    #pragma unroll
    for (int k = 0; k < FULL_K; ++k) {
        const int q = tid + TPB * k;
        GLOAD_LDS16(src + 4 * q, wf + 4 * q);
    }
    if (tid < TAIL_Q) {          // lanes 0..57 of wave 2 active; lane 0 live
        const int q = FULL_K * TPB + tid;
        GLOAD_LDS16(src + 4 * q, wf + 4 * q);
    }
    __syncthreads();             // barrier drains vmcnt -> LDS data ready

    // ---- Per-channel max/min, 6-way split over T.
    // thread = ch + 40*g (g in 0..5); iteration k reads LDS addr 240k+tid
    // -> lane-contiguous, conflict-free.
    if (tid < 6 * N_C) {
        const int ch = tid % N_C;
        const int g  = tid / N_C;
        float mx = -INFINITY, mn = INFINITY;
        for (int t = g; t < N_T; t += 6) {
            const float v = wf[t * N_C + ch];
            mx = fmaxf(mx, v);
            mn = fminf(mn, v);
        }
        pmx[tid] = mx;
        pmn[tid] = mn;
    }
    __syncthreads();

    // ---- Reduce the 6 partials -> ptp per channel.
    if (tid < N_C) {
        float mx = pmx[tid], mn = pmn[tid];
        #pragma unroll
        for (int g = 1; g < 6; ++g) {
            mx = fmaxf(mx, pmx[g * N_C + tid]);
            mn = fminf(mn, pmn[g * N_C + tid]);
        }
        ptp[tid] = mx - mn;
    }
    __syncthreads();

    // ---- Parent-min gather + rescaling + decreasing_ptps output.
    if (tid < N_C) {
        const int  mc   = max_channels[n];
        const int* prow = parents_index + mc * (N_C * N_P) + tid * N_P;
        float minp = INFINITY;
        #pragma unroll
        for (int p = 0; p < N_P; ++p) {
            const int idx = prow[p];
            minp = fminf(minp, (idx >= N_C) ? INFINITY : ptp[idx]);
        }
        const float r = fminf(minp / ptp[tid], 1.0f);
        resc[tid] = r;
        // decreasing_ptps, second output, offset N*T*c
        out[(size_t)n_total * WF_ELEMS + (size_t)n * N_C + tid] = ptp[tid] * r;
    }
    __syncthreads();

    // ---- Rescaled waveform from LDS, float4 stores.
    // 40 % 4 == 0 -> channels of one quad are ch0..ch0+3, never wrapping.
    const float4* wf4  = (const float4*)wf;
    float4*       dst4 = (float4*)(out + (size_t)n * WF_ELEMS);
    #pragma unroll
    for (int i = tid; i < WF_QUADS; i += TPB) {
        float4 v = wf4[i];
        const int ch0 = (i * 4) % N_C;
        v.x *= resc[ch0];
        v.y *= resc[ch0 + 1];
        v.z *= resc[ch0 + 2];
        v.w *= resc[ch0 + 3];
        dst4[i] = v;
    }
}

extern "C" void kernel_launch(void* const* d_in, const int* in_sizes, int n_in,
                              void* d_out, int out_size, void* d_ws, size_t ws_size,
                              hipStream_t stream) {
    const float* waveforms     = (const float*)d_in[0];
    const int*   max_channels  = (const int*)d_in[1];
    const int*   parents_index = (const int*)d_in[2];
    float*       out           = (float*)d_out;

    const int n = in_sizes[1];  // N = 8192 (element count of max_channels)

    enforce_decrease_kernel<<<dim3(n), dim3(TPB), 0, stream>>>(
        waveforms, max_channels, parents_index, out, n);
}

// Round 8
// 55.777 us; speedup vs baseline: 1.3367x; 1.1734x over previous
//
#include <hip/hip_runtime.h>
#include <math.h>

// EnforceDecrease: one workgroup per spike n.
//   ptps = wf.max(T) - wf.min(T)                         (per channel)
//   parent_min = min over P parents of padded ptps       (pad idx c -> +inf)
//   resc = min(parent_min / ptps, 1)
//   out0 = wf * resc[:, None, :]   out1 = ptps * resc
//
// R6: global_load_lds staging (74.5 -> 65.4 us).
// R7/R8: NON-TEMPORAL output stores (via clang ext_vector float4 -- HIP's
// float4 class is rejected by the builtin). FETCH_SIZE=83MB showed the
// 158MB input is only half-retained in L3 across replays -- the 160MB
// output stream was evicting it. nt stores keep the output out of L3 so
// the input stays resident; HBM traffic should approach write-only.

#define N_T 121
#define N_C 40
#define N_P 12
#define TPB 256
#define WF_ELEMS (N_T * N_C)      // 4840 floats
#define WF_QUADS (WF_ELEMS / 4)   // 1210 float4 quads
#define FULL_K   (WF_QUADS / TPB) // 4 full rounds = 1024 quads
#define TAIL_Q   (WF_QUADS - FULL_K * TPB) // 186 tail quads

typedef float f32x4 __attribute__((ext_vector_type(4)));

#define GLOAD_LDS16(g, l)                                              \
    __builtin_amdgcn_global_load_lds(                                  \
        (const __attribute__((address_space(1))) void*)(g),            \
        (__attribute__((address_space(3))) void*)(l), 16, 0, 0)

__global__ __launch_bounds__(TPB) void enforce_decrease_kernel(
    const float* __restrict__ waveforms,
    const int*   __restrict__ max_channels,
    const int*   __restrict__ parents_index,
    float*       __restrict__ out,
    int n_total)
{
    __shared__ float wf[WF_ELEMS];
    __shared__ float pmx[6 * N_C];
    __shared__ float pmn[6 * N_C];
    __shared__ float ptp[N_C];
    __shared__ float resc[N_C];

    const int n   = blockIdx.x;
    const int tid = threadIdx.x;

    // ---- Stage waveform n into LDS via direct global->LDS DMA.
    // LDS layout is linear in lane order (quad i -> LDS byte 16*i), which is
    // exactly the wave-uniform-base + lane*16 pattern the DMA requires.
    const float* src = waveforms + (size_t)n * WF_ELEMS;
    #pragma unroll
    for (int k = 0; k < FULL_K; ++k) {
        const int q = tid + TPB * k;
        GLOAD_LDS16(src + 4 * q, wf + 4 * q);
    }
    if (tid < TAIL_Q) {          // lanes 0..57 of wave 2 active; lane 0 live
        const int q = FULL_K * TPB + tid;
        GLOAD_LDS16(src + 4 * q, wf + 4 * q);
    }
    __syncthreads();             // barrier drains vmcnt -> LDS data ready

    // ---- Per-channel max/min, 6-way split over T.
    // thread = ch + 40*g (g in 0..5); iteration k reads LDS addr 240k+tid
    // -> lane-contiguous, conflict-free.
    if (tid < 6 * N_C) {
        const int ch = tid % N_C;
        const int g  = tid / N_C;
        float mx = -INFINITY, mn = INFINITY;
        for (int t = g; t < N_T; t += 6) {
            const float v = wf[t * N_C + ch];
            mx = fmaxf(mx, v);
            mn = fminf(mn, v);
        }
        pmx[tid] = mx;
        pmn[tid] = mn;
    }
    __syncthreads();

    // ---- Reduce the 6 partials -> ptp per channel.
    if (tid < N_C) {
        float mx = pmx[tid], mn = pmn[tid];
        #pragma unroll
        for (int g = 1; g < 6; ++g) {
            mx = fmaxf(mx, pmx[g * N_C + tid]);
            mn = fminf(mn, pmn[g * N_C + tid]);
        }
        ptp[tid] = mx - mn;
    }
    __syncthreads();

    // ---- Parent-min gather + rescaling + decreasing_ptps output.
    if (tid < N_C) {
        const int  mc   = max_channels[n];
        const int* prow = parents_index + mc * (N_C * N_P) + tid * N_P;
        float minp = INFINITY;
        #pragma unroll
        for (int p = 0; p < N_P; ++p) {
            const int idx = prow[p];
            minp = fminf(minp, (idx >= N_C) ? INFINITY : ptp[idx]);
        }
        const float r = fminf(minp / ptp[tid], 1.0f);
        resc[tid] = r;
        // decreasing_ptps, second output, offset N*T*c -- nt store
        __builtin_nontemporal_store(
            ptp[tid] * r,
            out + (size_t)n_total * WF_ELEMS + (size_t)n * N_C + tid);
    }
    __syncthreads();

    // ---- Rescaled waveform from LDS, non-temporal 16B stores.
    // 40 % 4 == 0 -> channels of one quad are ch0..ch0+3, never wrapping.
    const f32x4* wf4  = (const f32x4*)wf;
    f32x4*       dst4 = (f32x4*)(out + (size_t)n * WF_ELEMS);
    #pragma unroll
    for (int i = tid; i < WF_QUADS; i += TPB) {
        f32x4 v = wf4[i];
        const int ch0 = (i * 4) % N_C;
        v.x *= resc[ch0];
        v.y *= resc[ch0 + 1];
        v.z *= resc[ch0 + 2];
        v.w *= resc[ch0 + 3];
        __builtin_nontemporal_store(v, &dst4[i]);
    }
}

extern "C" void kernel_launch(void* const* d_in, const int* in_sizes, int n_in,
                              void* d_out, int out_size, void* d_ws, size_t ws_size,
                              hipStream_t stream) {
    const float* waveforms     = (const float*)d_in[0];
    const int*   max_channels  = (const int*)d_in[1];
    const int*   parents_index = (const int*)d_in[2];
    float*       out           = (float*)d_out;

    const int n = in_sizes[1];  // N = 8192 (element count of max_channels)

    enforce_decrease_kernel<<<dim3(n), dim3(TPB), 0, stream>>>(
        waveforms, max_channels, parents_index, out, n);
}